// Round 2
// baseline (681.981 us; speedup 1.0000x reference)
//
#include <hip/hip_runtime.h>

#define B_ 4
#define S_ 4096
#define E_ 2048
#define H_ 128

using f32x4 = __attribute__((ext_vector_type(4))) float;
using s16x8 = __attribute__((ext_vector_type(8))) short;
using s16x4 = __attribute__((ext_vector_type(4))) short;

// fp32 -> bf16 bits, round-to-nearest-even
__device__ __forceinline__ short f2bf(float f) {
  unsigned u = __float_as_uint(f);
  u += 0x7FFFu + ((u >> 16) & 1u);
  return (short)(u >> 16);
}

// ---------------------------------------------------------------------------
// Kernel 1: W (E x H fp32) x3 -> Wt (384 x 2048 bf16), row p*128+h holds W_p[:,h]
// ---------------------------------------------------------------------------
__global__ __launch_bounds__(256) void prep_weights(
    const float* __restrict__ Wq, const float* __restrict__ Wk,
    const float* __restrict__ Wv, short* __restrict__ Wt) {
  int p = blockIdx.y;
  const float* W = (p == 0) ? Wq : ((p == 1) ? Wk : Wv);
  int id = blockIdx.x * 256 + threadIdx.x;  // 0 .. E*H-1 (grid.x = 1024)
  int h = id >> 11;                          // / E_
  int e = id & (E_ - 1);
  Wt[(size_t)(p * H_ + h) * E_ + e] = f2bf(W[(size_t)e * H_ + h]);
}

// ---------------------------------------------------------------------------
// Kernel 2: fused QKV projection GEMM.
// C(16384 x 384) = x(16384 x 2048) @ Wt^T ; block = 32 rows x 384 cols, BK=32.
// 512 blocks -> 2 blocks/CU, 8 waves/CU (v1 had 256 blocks = 4 waves/CU,
// latency-bound). Wave w: both m-groups, cols [w*96, w*96+96).
// Q,K written [b*S+s][h]; V written TRANSPOSED Vt[b][h][s] for attention.
// ---------------------------------------------------------------------------
__global__ __launch_bounds__(256) void qkv_gemm(
    const float* __restrict__ x, const short* __restrict__ Wt,
    const float* __restrict__ bq, const float* __restrict__ bk,
    const float* __restrict__ bv,
    short* __restrict__ Q, short* __restrict__ K, short* __restrict__ Vt) {
  __shared__ __attribute__((aligned(16))) short xa[32 * 40];
  __shared__ __attribute__((aligned(16))) short wb[384 * 40];

  const int tid = threadIdx.x;
  const int wave = tid >> 6;
  const int lane = tid & 63;
  const int l15 = lane & 15;
  const int quad = lane >> 4;
  const int row0 = blockIdx.x * 32;

  f32x4 acc[2][6];
#pragma unroll
  for (int mg = 0; mg < 2; ++mg)
#pragma unroll
    for (int nt = 0; nt < 6; ++nt) acc[mg][nt] = (f32x4){0.f, 0.f, 0.f, 0.f};

  const int sr = tid >> 3;        // x staging row 0..31
  const int sc4 = (tid & 7) * 4;  // x staging col offset 0,4,..28

  for (int it = 0; it < 64; ++it) {
    const int k0 = it * 32;
    __syncthreads();
    // stage x tile (fp32 -> bf16), one float4 per thread
    {
      const float* xp = x + (size_t)(row0 + sr) * E_ + k0 + sc4;
      float4 f0 = *(const float4*)(xp);
      s16x4 xv;
      xv[0] = f2bf(f0.x); xv[1] = f2bf(f0.y); xv[2] = f2bf(f0.z); xv[3] = f2bf(f0.w);
      *(s16x4*)&xa[sr * 40 + sc4] = xv;
    }
    // stage Wt tile (bf16 copy): 384*32 shorts = 6 x s16x8 per thread
#pragma unroll
    for (int i2 = 0; i2 < 6; ++i2) {
      int id = tid + 256 * i2;   // 0..1535
      int r = id >> 2;           // 0..383
      int off = (id & 3) * 8;    // 0..24
      *(s16x8*)&wb[r * 40 + off] =
          *(const s16x8*)(Wt + (size_t)r * E_ + k0 + off);
    }
    __syncthreads();

    s16x8 af[2], bfr[6];
#pragma unroll
    for (int mg = 0; mg < 2; ++mg)
      af[mg] = *(const s16x8*)&xa[(mg * 16 + l15) * 40 + quad * 8];
#pragma unroll
    for (int nt = 0; nt < 6; ++nt)
      bfr[nt] = *(const s16x8*)&wb[(wave * 96 + nt * 16 + l15) * 40 + quad * 8];
#pragma unroll
    for (int mg = 0; mg < 2; ++mg)
#pragma unroll
      for (int nt = 0; nt < 6; ++nt)
        acc[mg][nt] = __builtin_amdgcn_mfma_f32_16x16x32_bf16(
            af[mg], bfr[nt], acc[mg][nt], 0, 0, 0);
  }

  // epilogue
  const int b = row0 >> 12;            // / S_
  const int s_base = row0 & (S_ - 1);  // % S_
#pragma unroll
  for (int nt = 0; nt < 6; ++nt) {
    int col = wave * 96 + nt * 16 + l15;
    int p = col >> 7;
    int h = col & (H_ - 1);
    if (p == 2) {  // V -> transposed Vt[b][h][s], packed 8B stores
      float bsv = bv[h];
#pragma unroll
      for (int mg = 0; mg < 2; ++mg) {
        int s0 = s_base + mg * 16 + quad * 4;
        s16x4 vv;
#pragma unroll
        for (int r = 0; r < 4; ++r) vv[r] = f2bf(acc[mg][nt][r] + bsv);
        *(s16x4*)&Vt[((size_t)b * H_ + h) * S_ + s0] = vv;
      }
    } else {
      const float* bias = (p == 0) ? bq : bk;
      short* dst = (p == 0) ? Q : K;
      float bsv = bias[h];
#pragma unroll
      for (int mg = 0; mg < 2; ++mg)
#pragma unroll
        for (int r = 0; r < 4; ++r) {
          int row = row0 + mg * 16 + quad * 4 + r;
          dst[(size_t)row * H_ + h] = f2bf(acc[mg][nt][r] + bsv);
        }
    }
  }
}

// ---------------------------------------------------------------------------
// Kernel 3: causal flash attention, ONE WAVE PER 16-ROW Q-TILE, no barriers.
// 1024 blocks x 64 threads, heavy tiles dispatched first (load balance).
// K b-frags and V b-frags read straight from global (K [s][h], Vt [h][s]);
// only the P C->A layout round-trip uses LDS (per-wave, lgkmcnt sync only).
// ---------------------------------------------------------------------------
__global__ __launch_bounds__(64) void flash_attn(
    const short* __restrict__ Qb, const short* __restrict__ Kb,
    const short* __restrict__ Vtb, float* __restrict__ out) {
  __shared__ __attribute__((aligned(16))) short p_lds[16 * 72];

  const int lane = threadIdx.x;
  const int l15 = lane & 15;
  const int quad = lane >> 4;
  // heavy-first mapping: tile 255 (64 k-iters) scheduled before tile 0 (1)
  const int tile = 255 - (blockIdx.x >> 2);
  const int b = blockIdx.x & 3;
  const int q0 = tile * 16;
  const size_t bo = (size_t)b * S_ * H_;
  const short* Vb = Vtb + (size_t)b * H_ * S_;  // [h][s]
  const float scale = 0.08838834764831845f;     // 1/sqrt(128)
  const float L2E = 1.4426950408889634f;
  const int n_k = (tile >> 2) + 1;  // 64-key tiles

  s16x8 aq[4];
#pragma unroll
  for (int kt = 0; kt < 4; ++kt)
    aq[kt] = *(const s16x8*)(Qb + bo + (size_t)(q0 + l15) * H_ + kt * 32 + quad * 8);

  f32x4 oacc[8];
#pragma unroll
  for (int nt = 0; nt < 8; ++nt) oacc[nt] = (f32x4){0.f, 0.f, 0.f, 0.f};
  float m_r[4], l_r[4];
#pragma unroll
  for (int r = 0; r < 4; ++r) { m_r[r] = -3.0e38f; l_r[r] = 0.f; }

  for (int i = 0; i < n_k; ++i) {
    const int kb = i * 64;
    // scores S = Q @ K^T (16 x 64)
    f32x4 sc[4];
#pragma unroll
    for (int nt = 0; nt < 4; ++nt) {
      f32x4 a = (f32x4){0.f, 0.f, 0.f, 0.f};
      const short* kp = Kb + bo + (size_t)(kb + nt * 16 + l15) * H_ + quad * 8;
#pragma unroll
      for (int kt = 0; kt < 4; ++kt)
        a = __builtin_amdgcn_mfma_f32_16x16x32_bf16(
            aq[kt], *(const s16x8*)(kp + kt * 32), a, 0, 0, 0);
#pragma unroll
      for (int r = 0; r < 4; ++r) a[r] *= scale;
      sc[nt] = a;
    }
    if (i == n_k - 1) {  // diagonal tile: causal mask (local coords)
      const int qloc = (tile & 3) * 16 + quad * 4;
#pragma unroll
      for (int nt = 0; nt < 4; ++nt)
#pragma unroll
        for (int r = 0; r < 4; ++r)
          if (nt * 16 + l15 > qloc + r) sc[nt][r] = -3.0e38f;
    }
    // row max (cols of a row live in the 16 lanes of its quad)
    float vm[4];
#pragma unroll
    for (int r = 0; r < 4; ++r)
      vm[r] = fmaxf(fmaxf(sc[0][r], sc[1][r]), fmaxf(sc[2][r], sc[3][r]));
#pragma unroll
    for (int off = 1; off < 16; off <<= 1)
#pragma unroll
      for (int r = 0; r < 4; ++r) vm[r] = fmaxf(vm[r], __shfl_xor(vm[r], off));

    float al[4];
#pragma unroll
    for (int r = 0; r < 4; ++r) {
      float mn = fmaxf(m_r[r], vm[r]);
      al[r] = exp2f((m_r[r] - mn) * L2E);
      m_r[r] = mn;
    }
    float rs[4] = {0.f, 0.f, 0.f, 0.f};
#pragma unroll
    for (int nt = 0; nt < 4; ++nt)
#pragma unroll
      for (int r = 0; r < 4; ++r) {
        float pv = exp2f((sc[nt][r] - m_r[r]) * L2E);
        sc[nt][r] = pv;
        rs[r] += pv;
      }
#pragma unroll
    for (int off = 1; off < 16; off <<= 1)
#pragma unroll
      for (int r = 0; r < 4; ++r) rs[r] += __shfl_xor(rs[r], off);
#pragma unroll
    for (int r = 0; r < 4; ++r) l_r[r] = l_r[r] * al[r] + rs[r];
#pragma unroll
    for (int nt = 0; nt < 8; ++nt)
#pragma unroll
      for (int r = 0; r < 4; ++r) oacc[nt][r] *= al[r];

    // P (C-layout) -> LDS -> A-layout. Single wave: lgkmcnt(0) is enough;
    // avoid __syncthreads (would drain vmcnt and kill K/V load pipelining).
    __asm__ volatile("s_waitcnt lgkmcnt(0)" ::: "memory");  // WAR vs prior reads
#pragma unroll
    for (int nt = 0; nt < 4; ++nt)
#pragma unroll
      for (int r = 0; r < 4; ++r)
        p_lds[(quad * 4 + r) * 72 + nt * 16 + l15] = f2bf(sc[nt][r]);
    __asm__ volatile("s_waitcnt lgkmcnt(0)" ::: "memory");  // RAW: writes visible

    s16x8 ap[2];
#pragma unroll
    for (int kt2 = 0; kt2 < 2; ++kt2)
      ap[kt2] = *(const s16x8*)&p_lds[l15 * 72 + kt2 * 32 + quad * 8];

    // O += P @ V, V b-frags straight from Vt[h][s] (contiguous in s)
#pragma unroll
    for (int nt = 0; nt < 8; ++nt) {
      const short* vp = Vb + (size_t)(nt * 16 + l15) * S_ + kb + quad * 8;
#pragma unroll
      for (int kt2 = 0; kt2 < 2; ++kt2)
        oacc[nt] = __builtin_amdgcn_mfma_f32_16x16x32_bf16(
            ap[kt2], *(const s16x8*)(vp + kt2 * 32), oacc[nt], 0, 0, 0);
    }
  }

  float inv[4];
#pragma unroll
  for (int r = 0; r < 4; ++r) inv[r] = 1.0f / l_r[r];
#pragma unroll
  for (int nt = 0; nt < 8; ++nt)
#pragma unroll
    for (int r = 0; r < 4; ++r)
      out[bo + (size_t)(q0 + quad * 4 + r) * H_ + nt * 16 + l15] =
          oacc[nt][r] * inv[r];
}

// ---------------------------------------------------------------------------
extern "C" void kernel_launch(void* const* d_in, const int* in_sizes, int n_in,
                              void* d_out, int out_size, void* d_ws, size_t ws_size,
                              hipStream_t stream) {
  const float* x  = (const float*)d_in[0];
  const float* Wq = (const float*)d_in[1];
  const float* bq = (const float*)d_in[2];
  const float* Wk = (const float*)d_in[3];
  const float* bk = (const float*)d_in[4];
  const float* Wv = (const float*)d_in[5];
  const float* bv = (const float*)d_in[6];

  // ws layout: Wt (384*2048 bf16) | Q | K | Vt (each B*S*H bf16) ~= 13.5 MB
  short* Wt = (short*)d_ws;
  short* Q  = Wt + (size_t)384 * E_;
  short* K  = Q + (size_t)B_ * S_ * H_;
  short* Vt = K + (size_t)B_ * S_ * H_;
  float* out = (float*)d_out;

  hipLaunchKernelGGL(prep_weights, dim3(E_ * H_ / 256, 3), dim3(256), 0, stream,
                     Wq, Wk, Wv, Wt);
  hipLaunchKernelGGL(qkv_gemm, dim3((B_ * S_) / 32), dim3(256), 0, stream,
                     x, Wt, bq, bk, bv, Q, K, Vt);
  hipLaunchKernelGGL(flash_attn, dim3((S_ / 16) * B_), dim3(64), 0, stream,
                     Q, K, Vt, out);
}

// Round 3
// 407.211 us; speedup vs baseline: 1.6748x; 1.6748x over previous
//
#include <hip/hip_runtime.h>

#define B_ 4
#define S_ 4096
#define E_ 2048
#define H_ 128

using f32x4 = __attribute__((ext_vector_type(4))) float;
using s16x8 = __attribute__((ext_vector_type(8))) short;
using s16x4 = __attribute__((ext_vector_type(4))) short;

// fp32 -> bf16 bits, round-to-nearest-even
__device__ __forceinline__ short f2bf(float f) {
  unsigned u = __float_as_uint(f);
  u += 0x7FFFu + ((u >> 16) & 1u);
  return (short)(u >> 16);
}

// ---------------------------------------------------------------------------
// Kernel 1: W (E x H fp32) x3 -> Wt (384 x 2048 bf16) via LDS tile transpose.
// v1 read W column-wise (512B stride, uncoalesced). Tile 32e x 32h.
// ---------------------------------------------------------------------------
__global__ __launch_bounds__(256) void prep_weights(
    const float* __restrict__ Wq, const float* __restrict__ Wk,
    const float* __restrict__ Wv, short* __restrict__ Wt) {
  __shared__ float T[32 * 33];
  int p = blockIdx.y;
  const float* W = (p == 0) ? Wq : ((p == 1) ? Wk : Wv);
  int e0 = (blockIdx.x & 63) * 32;   // E/32 = 64 tiles
  int h0 = (blockIdx.x >> 6) * 32;   // H/32 = 4 tiles
  int r = threadIdx.x >> 5;          // 0..7
  int c = threadIdx.x & 31;
#pragma unroll
  for (int i = 0; i < 4; ++i) {      // read coalesced in h
    int e = r + 8 * i;
    T[c * 33 + e] = W[(size_t)(e0 + e) * H_ + h0 + c];
  }
  __syncthreads();
#pragma unroll
  for (int i = 0; i < 4; ++i) {      // write coalesced in e
    int h = r + 8 * i;
    Wt[(size_t)(p * H_ + h0 + h) * E_ + e0 + c] = f2bf(T[h * 33 + c]);
  }
}

// ---------------------------------------------------------------------------
// Kernel 2: fused QKV projection GEMM with register-prefetch pipeline.
// C(16384 x 384) = x(16384 x 2048) @ Wt^T ; block = 32 rows x 384 cols, BK=32.
// 512 blocks = 2 blocks/CU, 8 waves/CU. Global loads for tile k+1 issued
// right after the store-barrier, overlapping latency with tile-k MFMAs.
// Q is written PRE-SCALED by 1/sqrt(H); V written transposed Vt[b][h][s].
// ---------------------------------------------------------------------------
__global__ __launch_bounds__(256, 3) void qkv_gemm(
    const float* __restrict__ x, const short* __restrict__ Wt,
    const float* __restrict__ bq, const float* __restrict__ bk,
    const float* __restrict__ bv,
    short* __restrict__ Q, short* __restrict__ K, short* __restrict__ Vt) {
  __shared__ __attribute__((aligned(16))) short xa[32 * 40];
  __shared__ __attribute__((aligned(16))) short wb[384 * 40];

  const int tid = threadIdx.x;
  const int wave = tid >> 6;
  const int lane = tid & 63;
  const int l15 = lane & 15;
  const int quad = lane >> 4;
  const int row0 = blockIdx.x * 32;

  f32x4 acc[2][6];
#pragma unroll
  for (int mg = 0; mg < 2; ++mg)
#pragma unroll
    for (int nt = 0; nt < 6; ++nt) acc[mg][nt] = (f32x4){0.f, 0.f, 0.f, 0.f};

  // staging coords
  const int sr = tid >> 3;          // x row 0..31
  const int sc4 = (tid & 7) * 4;    // x col 0,4..28
  const int wr = tid >> 2;          // W row base 0..63 (+64*i2)
  const int wo = (tid & 3) * 8;     // W col 0,8,16,24
  const float* xp = x + (size_t)(row0 + sr) * E_ + sc4;
  const short* wp = Wt + (size_t)wr * E_ + wo;

  // prefetch tile 0
  float4 xf = *(const float4*)(xp);
  s16x8 wreg[6];
#pragma unroll
  for (int i2 = 0; i2 < 6; ++i2)
    wreg[i2] = *(const s16x8*)(wp + (size_t)(64 * i2) * E_);

  for (int it = 0; it < 64; ++it) {
    __syncthreads();  // LDS free (previous iter's readers done)
    {
      s16x4 xv;
      xv[0] = f2bf(xf.x); xv[1] = f2bf(xf.y); xv[2] = f2bf(xf.z); xv[3] = f2bf(xf.w);
      *(s16x4*)&xa[sr * 40 + sc4] = xv;
    }
#pragma unroll
    for (int i2 = 0; i2 < 6; ++i2)
      *(s16x8*)&wb[(wr + 64 * i2) * 40 + wo] = wreg[i2];
    __syncthreads();

    if (it < 63) {  // prefetch next tile (overlaps with MFMAs below)
      const int k0n = (it + 1) * 32;
      xf = *(const float4*)(xp + k0n);
#pragma unroll
      for (int i2 = 0; i2 < 6; ++i2)
        wreg[i2] = *(const s16x8*)(wp + (size_t)(64 * i2) * E_ + k0n);
    }

    s16x8 af[2], bfr[6];
#pragma unroll
    for (int mg = 0; mg < 2; ++mg)
      af[mg] = *(const s16x8*)&xa[(mg * 16 + l15) * 40 + quad * 8];
#pragma unroll
    for (int nt = 0; nt < 6; ++nt)
      bfr[nt] = *(const s16x8*)&wb[(wave * 96 + nt * 16 + l15) * 40 + quad * 8];
#pragma unroll
    for (int mg = 0; mg < 2; ++mg)
#pragma unroll
      for (int nt = 0; nt < 6; ++nt)
        acc[mg][nt] = __builtin_amdgcn_mfma_f32_16x16x32_bf16(
            af[mg], bfr[nt], acc[mg][nt], 0, 0, 0);
  }

  // epilogue
  const float scale = 0.08838834764831845f;  // 1/sqrt(128), folded into Q
  const int b = row0 >> 12;
  const int s_base = row0 & (S_ - 1);
#pragma unroll
  for (int nt = 0; nt < 6; ++nt) {
    int col = wave * 96 + nt * 16 + l15;
    int p = col >> 7;
    int h = col & (H_ - 1);
    if (p == 2) {  // V -> Vt[b][h][s], packed 8B stores
      float bsv = bv[h];
#pragma unroll
      for (int mg = 0; mg < 2; ++mg) {
        int s0 = s_base + mg * 16 + quad * 4;
        s16x4 vv;
#pragma unroll
        for (int r = 0; r < 4; ++r) vv[r] = f2bf(acc[mg][nt][r] + bsv);
        *(s16x4*)&Vt[((size_t)b * H_ + h) * S_ + s0] = vv;
      }
    } else if (p == 0) {  // Q, pre-scaled
      float bsv = bq[h];
#pragma unroll
      for (int mg = 0; mg < 2; ++mg)
#pragma unroll
        for (int r = 0; r < 4; ++r) {
          int row = row0 + mg * 16 + quad * 4 + r;
          Q[(size_t)row * H_ + h] = f2bf((acc[mg][nt][r] + bsv) * scale);
        }
    } else {
      float bsv = bk[h];
#pragma unroll
      for (int mg = 0; mg < 2; ++mg)
#pragma unroll
        for (int r = 0; r < 4; ++r) {
          int row = row0 + mg * 16 + quad * 4 + r;
          K[(size_t)row * H_ + h] = f2bf(acc[mg][nt][r] + bsv);
        }
    }
  }
}

// ---------------------------------------------------------------------------
// Kernel 3: causal flash attention with intra-block K-SPLIT.
// Block (256 thr) = one 16-row q-tile; wave w processes k-tiles w, w+4, ...
// with private online-softmax state; end-of-block (m,l,O) merge via LDS.
// 1024 blocks x 4 waves, ~34KB LDS -> 4 blocks/CU = 4 waves/SIMD.
// Q is pre-scaled by 1/sqrt(H). K read [s][h], V read transposed [h][s].
// ---------------------------------------------------------------------------
__global__ __launch_bounds__(256, 3) void flash_attn(
    const short* __restrict__ Qb, const short* __restrict__ Kb,
    const short* __restrict__ Vtb, float* __restrict__ out) {
  __shared__ __attribute__((aligned(16))) float Ob[4 * 16 * 132];  // 33792 B
  __shared__ float mlds[64], llds[64];

  const int tid = threadIdx.x;
  const int w = tid >> 6;
  const int lane = tid & 63;
  const int l15 = lane & 15;
  const int quad = lane >> 4;
  const int t = 255 - (blockIdx.x >> 2);  // heavy q-tiles first
  const int b = blockIdx.x & 3;
  const int q0 = t * 16;
  const size_t bo = (size_t)b * S_ * H_;
  const short* Vb = Vtb + (size_t)b * H_ * S_;  // [h][s]
  const float L2E = 1.4426950408889634f;
  const int nk = (t >> 2) + 1;  // 64-key tiles covering causal range

  // per-wave P scratch aliased onto this wave's Ob region (used only in loop)
  short* p_lds = (short*)&Ob[w * (16 * 132)];

  s16x8 aq[4];
#pragma unroll
  for (int kt = 0; kt < 4; ++kt)
    aq[kt] = *(const s16x8*)(Qb + bo + (size_t)(q0 + l15) * H_ + kt * 32 + quad * 8);

  f32x4 oacc[8];
#pragma unroll
  for (int nt = 0; nt < 8; ++nt) oacc[nt] = (f32x4){0.f, 0.f, 0.f, 0.f};
  float m_r[4], l_r[4];
#pragma unroll
  for (int r = 0; r < 4; ++r) { m_r[r] = -3.0e38f; l_r[r] = 0.f; }

  for (int i = w; i < nk; i += 4) {
    const int kb = i * 64;
    // scores S = Q @ K^T (16 x 64), Q pre-scaled
    f32x4 sc[4];
#pragma unroll
    for (int nt = 0; nt < 4; ++nt) {
      f32x4 a = (f32x4){0.f, 0.f, 0.f, 0.f};
      const short* kp = Kb + bo + (size_t)(kb + nt * 16 + l15) * H_ + quad * 8;
#pragma unroll
      for (int kt = 0; kt < 4; ++kt)
        a = __builtin_amdgcn_mfma_f32_16x16x32_bf16(
            aq[kt], *(const s16x8*)(kp + kt * 32), a, 0, 0, 0);
      sc[nt] = a;
    }
    if (i == nk - 1) {  // diagonal k-tile: causal mask (local coords)
      const int qloc = (t & 3) * 16 + quad * 4;
#pragma unroll
      for (int nt = 0; nt < 4; ++nt)
#pragma unroll
        for (int r = 0; r < 4; ++r)
          if (nt * 16 + l15 > qloc + r) sc[nt][r] = -3.0e38f;
    }
    // row max across the quad's 16 lanes
    float vm[4];
#pragma unroll
    for (int r = 0; r < 4; ++r)
      vm[r] = fmaxf(fmaxf(sc[0][r], sc[1][r]), fmaxf(sc[2][r], sc[3][r]));
#pragma unroll
    for (int off = 1; off < 16; off <<= 1)
#pragma unroll
      for (int r = 0; r < 4; ++r) vm[r] = fmaxf(vm[r], __shfl_xor(vm[r], off));

    float al[4];
#pragma unroll
    for (int r = 0; r < 4; ++r) {
      float mn = fmaxf(m_r[r], vm[r]);
      al[r] = exp2f((m_r[r] - mn) * L2E);
      m_r[r] = mn;
    }
    float rs[4] = {0.f, 0.f, 0.f, 0.f};
#pragma unroll
    for (int nt = 0; nt < 4; ++nt)
#pragma unroll
      for (int r = 0; r < 4; ++r) {
        float pv = exp2f((sc[nt][r] - m_r[r]) * L2E);
        sc[nt][r] = pv;
        rs[r] += pv;
      }
#pragma unroll
    for (int off = 1; off < 16; off <<= 1)
#pragma unroll
      for (int r = 0; r < 4; ++r) rs[r] += __shfl_xor(rs[r], off);
#pragma unroll
    for (int r = 0; r < 4; ++r) l_r[r] = l_r[r] * al[r] + rs[r];
#pragma unroll
    for (int nt = 0; nt < 8; ++nt)
#pragma unroll
      for (int r = 0; r < 4; ++r) oacc[nt][r] *= al[r];

    // P (C-layout) -> per-wave LDS -> A-layout bf16 (wave-local, no barrier)
    __asm__ volatile("s_waitcnt lgkmcnt(0)" ::: "memory");
#pragma unroll
    for (int nt = 0; nt < 4; ++nt)
#pragma unroll
      for (int r = 0; r < 4; ++r)
        p_lds[(quad * 4 + r) * 72 + nt * 16 + l15] = f2bf(sc[nt][r]);
    __asm__ volatile("s_waitcnt lgkmcnt(0)" ::: "memory");

    s16x8 ap[2];
#pragma unroll
    for (int kt2 = 0; kt2 < 2; ++kt2)
      ap[kt2] = *(const s16x8*)&p_lds[l15 * 72 + kt2 * 32 + quad * 8];

    // O += P @ V from Vt[h][s]
#pragma unroll
    for (int nt = 0; nt < 8; ++nt) {
      const short* vp = Vb + (size_t)(nt * 16 + l15) * S_ + kb + quad * 8;
#pragma unroll
      for (int kt2 = 0; kt2 < 2; ++kt2)
        oacc[nt] = __builtin_amdgcn_mfma_f32_16x16x32_bf16(
            ap[kt2], *(const s16x8*)(vp + kt2 * 32), oacc[nt], 0, 0, 0);
    }
  }

  // ---- cross-wave merge of (m, l, O) ----
  if (l15 == 0) {
#pragma unroll
    for (int r = 0; r < 4; ++r) {
      mlds[w * 16 + quad * 4 + r] = m_r[r];
      llds[w * 16 + quad * 4 + r] = l_r[r];
    }
  }
#pragma unroll
  for (int nt = 0; nt < 8; ++nt)
#pragma unroll
    for (int r = 0; r < 4; ++r)
      Ob[w * (16 * 132) + (quad * 4 + r) * 132 + nt * 16 + l15] = oacc[nt][r];
  __syncthreads();

  // final: thread -> (row, 8 cols)
  const int row = tid >> 4;
  const int c0 = (tid & 15) * 8;
  float m0 = mlds[row], m1 = mlds[16 + row], m2 = mlds[32 + row], m3 = mlds[48 + row];
  float ms = fmaxf(fmaxf(m0, m1), fmaxf(m2, m3));
  float f0 = exp2f((m0 - ms) * L2E), f1 = exp2f((m1 - ms) * L2E);
  float f2 = exp2f((m2 - ms) * L2E), f3 = exp2f((m3 - ms) * L2E);
  float lf = llds[row] * f0 + llds[16 + row] * f1 + llds[32 + row] * f2 +
             llds[48 + row] * f3;
  float invl = 1.0f / lf;
  float o[8];
#pragma unroll
  for (int j = 0; j < 8; ++j) {
    int idx = row * 132 + c0 + j;
    o[j] = (f0 * Ob[idx] + f1 * Ob[16 * 132 + idx] + f2 * Ob[2 * 16 * 132 + idx] +
            f3 * Ob[3 * 16 * 132 + idx]) * invl;
  }
  float* op = out + bo + (size_t)(q0 + row) * H_ + c0;
  *(float4*)(op) = (float4){o[0], o[1], o[2], o[3]};
  *(float4*)(op + 4) = (float4){o[4], o[5], o[6], o[7]};
}

// ---------------------------------------------------------------------------
extern "C" void kernel_launch(void* const* d_in, const int* in_sizes, int n_in,
                              void* d_out, int out_size, void* d_ws, size_t ws_size,
                              hipStream_t stream) {
  const float* x  = (const float*)d_in[0];
  const float* Wq = (const float*)d_in[1];
  const float* bq = (const float*)d_in[2];
  const float* Wk = (const float*)d_in[3];
  const float* bk = (const float*)d_in[4];
  const float* Wv = (const float*)d_in[5];
  const float* bv = (const float*)d_in[6];

  // ws layout: Wt (384*2048 bf16) | Q | K | Vt (each B*S*H bf16) ~= 13.5 MB
  short* Wt = (short*)d_ws;
  short* Q  = Wt + (size_t)384 * E_;
  short* K  = Q + (size_t)B_ * S_ * H_;
  short* Vt = K + (size_t)B_ * S_ * H_;
  float* out = (float*)d_out;

  hipLaunchKernelGGL(prep_weights, dim3(64 * 4, 3), dim3(256), 0, stream,
                     Wq, Wk, Wv, Wt);
  hipLaunchKernelGGL(qkv_gemm, dim3((B_ * S_) / 32), dim3(256), 0, stream,
                     x, Wt, bq, bk, bv, Q, K, Vt);
  hipLaunchKernelGGL(flash_attn, dim3((S_ / 16) * B_), dim3(256), 0, stream,
                     Q, K, Vt, out);
}